// Round 12
// baseline (391.447 us; speedup 1.0000x reference)
//
#include <hip/hip_runtime.h>
#include <hip/hip_bf16.h>

typedef __hip_bfloat16 bf16;
typedef short bf16x8 __attribute__((ext_vector_type(8)));
typedef float f32x4 __attribute__((ext_vector_type(4)));

#define BBATCH 8
#define HHH 56
#define WWW 56
#define CCH 96          // C
#define DIN 192         // D
#define NST 16          // N
#define KDIR 4          // K
#define RDT 6           // R
#define LLEN 3136       // H*W
#define BLTOT 25088     // B*L
#define SSEG 112        // segments (112 * 28 = 3136)
#define SEGL 28         // L / SSEG
#define PJC 38          // R + 2N
#define PJW 152         // K * PJC
#define PJS 40          // padded LDS row stride (16B aligned)
#define PJS1 24         // pass-1 padded row stride (r+B only)
#define MLPH 384

// native exp2/log2 (v_exp_f32 / v_log_f32) with safe fallbacks
#if defined(__has_builtin)
#if __has_builtin(__builtin_amdgcn_exp2f)
#define EXP2F(x) __builtin_amdgcn_exp2f(x)
#endif
#if __has_builtin(__builtin_amdgcn_logf)
#define LOG2F_(x) __builtin_amdgcn_logf(x)
#endif
#endif
#ifndef EXP2F
#define EXP2F(x) __expf((x) * 0.69314718056f)
#endif
#ifndef LOG2F_
#define LOG2F_(x) (__logf(x) * 1.44269504f)
#endif
#define LOG2E 1.44269504f

// packed fp32 (VOP3P, gfx90a+/gfx950)
__device__ __forceinline__ float2 pk_mul(float2 a, float2 b) {
    float2 d;
    asm("v_pk_mul_f32 %0, %1, %2" : "=v"(d) : "v"(a), "v"(b));
    return d;
}
__device__ __forceinline__ float2 pk_fma(float2 a, float2 b, float2 c) {
    float2 d;
    asm("v_pk_fma_f32 %0, %1, %2, %3" : "=v"(d) : "v"(a), "v"(b), "v"(c));
    return d;
}

__device__ __forceinline__ float b2f(bf16 v) { return __bfloat162float(v); }
__device__ __forceinline__ bf16  f2b(float v) { return __float2bfloat16(v); }
__device__ __forceinline__ unsigned short f2bu(float f) {
    union { bf16 h; unsigned short u; } c; c.h = __float2bfloat16(f); return c.u;
}
__device__ __forceinline__ float bu2f(unsigned short u) {
    union { unsigned short u; bf16 h; } c; c.u = u; return __bfloat162float(c.h);
}
__device__ __forceinline__ float sigm(float x) { return 1.f / (1.f + __expf(-x)); }
__device__ __forceinline__ float softplusf(float x) {
    float t = EXP2F(-fabsf(x) * LOG2E);
    return fmaxf(x, 0.f) + 0.69314718f * LOG2F_(1.f + t);
}
__device__ __forceinline__ float geluf(float v) {
    float u = 0.7978845608028654f * (v + 0.044715f * v * v * v);
    float ey = __expf(2.f * u);
    float th = 1.f - 2.f / (ey + 1.f);
    return 0.5f * v * (1.f + th);
}

// scan-step l -> spatial position (row-major h*56+w) for direction k
__device__ __forceinline__ int pos_map(int k, int l) {
    if (k & 2) l = LLEN - 1 - l;
    if (k & 1) { int q = l / WWW; int r = l - q * WWW; return r * WWW + q; }
    return l;
}

// ---- K0: precompute a2[k][d][n] = -exp(Alog)*log2e --------------------------
__global__ __launch_bounds__(256) void k0_pre(
    const float* __restrict__ Alog, float* __restrict__ a2g) {
    int i = blockIdx.x * 256 + threadIdx.x;   // over K*D*N = 12288
    a2g[i] = -__expf(Alog[i]) * LOG2E;
}

// ---- K0w: pre-convert the 5 GEMM weight matrices to bf16 --------------------
// layout in wbf: inpW@0(36864) xprojW@36864(29184) outW@66048(18432)
//               fc1W@84480(36864) fc2W@121344(36864)  total 158208
__global__ __launch_bounds__(256) void k0w(
    const float* __restrict__ w1, const float* __restrict__ w2,
    const float* __restrict__ w3, const float* __restrict__ w4,
    const float* __restrict__ w5, unsigned short* __restrict__ o) {
    int i = blockIdx.x * 256 + threadIdx.x;
    float v;
    if (i < 36864)       v = w1[i];
    else if (i < 66048)  v = w2[i - 36864];
    else if (i < 84480)  v = w3[i - 66048];
    else if (i < 121344) v = w4[i - 84480];
    else                 v = w5[i - 121344];
    o[i] = f2bu(v);
}

// ---- Unified MFMA GEMM, LDS-free: C[M][N] = A[M][K] . Wb[N][K]^T(bf16) -----
// block: 4 waves, each wave a 32-row M-strip x 64-col N-tile, 2x4 frags.
// No LDS, no barriers: each wave loads its own A/B fragments from global.
// LNIN: A is f32 (K must be 96) with LayerNorm fused in-register.
// EPI: 0=split xc/z  1=proj f32  2=+res f32  3=gelu(+bias) bf16  4=+bias+res f32
template<int N, int K, int EPI, bool LNIN>
__global__ __launch_bounds__(256) void gemm_mfma(
    const void* __restrict__ Xv, const unsigned short* __restrict__ Wb,
    const float* __restrict__ bias, const float* __restrict__ res,
    const float* __restrict__ lnw, const float* __restrict__ lnb,
    void* __restrict__ out0v, void* __restrict__ out1v) {
    const int t = threadIdx.x;
    const int P0 = blockIdx.x * 128;
    const int N0 = blockIdx.y * 64;
    const int w = t >> 6, lane = t & 63, q = lane >> 4, nl = lane & 15;
    f32x4 acc[2][4];
#pragma unroll
    for (int i = 0; i < 2; ++i)
#pragma unroll
        for (int j = 0; j < 4; ++j)
            acc[i][j] = (f32x4){0.f, 0.f, 0.f, 0.f};

    // B fragment pointers (clamped rows; B is tiny and L2-resident)
    const unsigned short* bp[4];
#pragma unroll
    for (int nf = 0; nf < 4; ++nf) {
        int ng = N0 + nf * 16 + nl; if (ng > N - 1) ng = N - 1;
        bp[nf] = &Wb[(size_t)ng * K + q * 8];
    }

    if constexpr (LNIN) {
        // K == 96. Preload both rows fully (3 iters x 8 f32), stats via shfl.
        const float* Xf = (const float*)Xv;
        float av[2][3][8];
        float mv[2], rv[2];
#pragma unroll
        for (int mf = 0; mf < 2; ++mf) {
            const float* rp = Xf + (size_t)(P0 + w * 32 + mf * 16 + nl) * 96 + q * 8;
            float s = 0.f, s2 = 0.f;
#pragma unroll
            for (int it = 0; it < 3; ++it) {
                float4 v0 = *(const float4*)(rp + it * 32);
                float4 v1 = *(const float4*)(rp + it * 32 + 4);
                av[mf][it][0] = v0.x; av[mf][it][1] = v0.y;
                av[mf][it][2] = v0.z; av[mf][it][3] = v0.w;
                av[mf][it][4] = v1.x; av[mf][it][5] = v1.y;
                av[mf][it][6] = v1.z; av[mf][it][7] = v1.w;
                s += v0.x + v0.y + v0.z + v0.w + v1.x + v1.y + v1.z + v1.w;
                s2 += v0.x * v0.x + v0.y * v0.y + v0.z * v0.z + v0.w * v0.w +
                      v1.x * v1.x + v1.y * v1.y + v1.z * v1.z + v1.w * v1.w;
            }
            s += __shfl_xor(s, 16); s2 += __shfl_xor(s2, 16);
            s += __shfl_xor(s, 32); s2 += __shfl_xor(s2, 32);
            float m = s * (1.f / 96.f);
            float var = s2 * (1.f / 96.f) - m * m;
            mv[mf] = m; rv[mf] = rsqrtf(var + 1e-5f);
        }
#pragma unroll
        for (int it = 0; it < 3; ++it) {
            int c0 = it * 32 + q * 8;
            float4 w0 = *(const float4*)&lnw[c0];
            float4 w1 = *(const float4*)&lnw[c0 + 4];
            float4 b0 = *(const float4*)&lnb[c0];
            float4 b1 = *(const float4*)&lnb[c0 + 4];
            float wj[8] = {w0.x, w0.y, w0.z, w0.w, w1.x, w1.y, w1.z, w1.w};
            float bj[8] = {b0.x, b0.y, b0.z, b0.w, b1.x, b1.y, b1.z, b1.w};
            bf16x8 af[2], bfr[4];
#pragma unroll
            for (int mf = 0; mf < 2; ++mf)
#pragma unroll
                for (int j = 0; j < 8; ++j)
                    af[mf][j] = (short)f2bu(
                        (av[mf][it][j] - mv[mf]) * rv[mf] * wj[j] + bj[j]);
#pragma unroll
            for (int nf = 0; nf < 4; ++nf)
                bfr[nf] = *(const bf16x8*)(bp[nf] + it * 32);
#pragma unroll
            for (int mf = 0; mf < 2; ++mf)
#pragma unroll
                for (int nf = 0; nf < 4; ++nf)
                    acc[mf][nf] = __builtin_amdgcn_mfma_f32_16x16x32_bf16(
                        af[mf], bfr[nf], acc[mf][nf], 0, 0, 0);
        }
    } else {
        const unsigned short* X = (const unsigned short*)Xv;
        const unsigned short* ap[2];
#pragma unroll
        for (int mf = 0; mf < 2; ++mf)
            ap[mf] = &X[(size_t)(P0 + w * 32 + mf * 16 + nl) * K + q * 8];
#pragma unroll
        for (int it = 0; it < K / 32; ++it) {
            bf16x8 af[2], bfr[4];
#pragma unroll
            for (int mf = 0; mf < 2; ++mf)
                af[mf] = *(const bf16x8*)(ap[mf] + it * 32);
#pragma unroll
            for (int nf = 0; nf < 4; ++nf)
                bfr[nf] = *(const bf16x8*)(bp[nf] + it * 32);
#pragma unroll
            for (int mf = 0; mf < 2; ++mf)
#pragma unroll
                for (int nf = 0; nf < 4; ++nf)
                    acc[mf][nf] = __builtin_amdgcn_mfma_f32_16x16x32_bf16(
                        af[mf], bfr[nf], acc[mf][nf], 0, 0, 0);
        }
    }
#pragma unroll
    for (int mf = 0; mf < 2; ++mf) {
#pragma unroll
        for (int nf = 0; nf < 4; ++nf) {
#pragma unroll
            for (int r = 0; r < 4; ++r) {
                float v = acc[mf][nf][r];
                size_t pos = (size_t)P0 + w * 32 + mf * 16 + q * 4 + r;
                int n = N0 + nf * 16 + nl;
                if constexpr (EPI == 0) {
                    unsigned short* xc = (unsigned short*)out0v;
                    unsigned short* zz = (unsigned short*)out1v;
                    if (n < 192) xc[pos * 192 + n] = f2bu(v);
                    else         zz[pos * 192 + (n - 192)] = f2bu(v);
                } else if constexpr (EPI == 1) {
                    if (n < 152) ((float*)out0v)[pos * 152 + n] = v;
                } else if constexpr (EPI == 2) {
                    if (n < 96) ((float*)out0v)[pos * 96 + n] = res[pos * 96 + n] + v;
                } else if constexpr (EPI == 3) {
                    ((unsigned short*)out0v)[pos * 384 + n] = f2bu(geluf(v + bias[n]));
                } else {
                    if (n < 96) ((float*)out0v)[pos * 96 + n] =
                        res[pos * 96 + n] + bias[n] + v;
                }
            }
        }
    }
}

// ---- K2: depthwise 3x3 conv + bias + silu, 4 channels/thread ---------------
__global__ __launch_bounds__(256) void k2_conv(
    const unsigned short* __restrict__ xcpre, const float* __restrict__ cw,
    const float* __restrict__ cb, unsigned short* __restrict__ xconv) {
    int idx = blockIdx.x * 256 + threadIdx.x;
    int dd = idx % 48;
    int P = idx / 48;
    int d0 = dd * 4;
    int b = P / LLEN, l = P - b * LLEN;
    int h = l / WWW, w = l - h * WWW;
    float acc0 = cb[d0], acc1 = cb[d0 + 1], acc2 = cb[d0 + 2], acc3 = cb[d0 + 3];
#pragma unroll
    for (int i = 0; i < 3; ++i) {
        int hh = h + i - 1;
        if (hh < 0 || hh >= HHH) continue;
#pragma unroll
        for (int j = 0; j < 3; ++j) {
            int ww = w + j - 1;
            if (ww < 0 || ww >= WWW) continue;
            ushort4 xv = *(const ushort4*)&xcpre[
                ((size_t)(b * LLEN + hh * WWW + ww)) * DIN + d0];
            acc0 = fmaf(bu2f(xv.x), cw[(d0 + 0) * 9 + i * 3 + j], acc0);
            acc1 = fmaf(bu2f(xv.y), cw[(d0 + 1) * 9 + i * 3 + j], acc1);
            acc2 = fmaf(bu2f(xv.z), cw[(d0 + 2) * 9 + i * 3 + j], acc2);
            acc3 = fmaf(bu2f(xv.w), cw[(d0 + 3) * 9 + i * 3 + j], acc3);
        }
    }
    acc0 = acc0 * sigm(acc0); acc1 = acc1 * sigm(acc1);
    acc2 = acc2 * sigm(acc2); acc3 = acc3 * sigm(acc3);
    ushort4 o;
    o.x = f2bu(acc0); o.y = f2bu(acc1); o.z = f2bu(acc2); o.w = f2bu(acc3);
    *(ushort4*)&xconv[(size_t)P * DIN + d0] = o;
}

// ---- K4: scan pass 1 — one segment per block, packed-fp32, fp32 h-out ------
__global__ __launch_bounds__(192) void k4_scan1(
    const bf16* __restrict__ xconv, const float* __restrict__ proj,
    const float* __restrict__ dtw, const float* __restrict__ dtb,
    const float* __restrict__ a2g, float* __restrict__ hloc,
    float* __restrict__ tsum) {
    __shared__ float pl[SEGL * PJS1];
    __shared__ int posl[SEGL];
    const int bid = blockIdx.x;              // 3584 = (b*4+k)*112 + s
    const int s = bid % SSEG;
    const int bk = bid / SSEG;
    const int k = bk & 3, b = bk >> 2;
    const int d = threadIdx.x;
    const int l0 = s * SEGL;
    for (int q = d; q < SEGL * 22; q += 192) {
        int st = q / 22, c = q - st * 22;
        int p = pos_map(k, l0 + st);
        int ofs = (c < 6) ? c : c + 2;
        pl[st * PJS1 + ofs] = proj[(size_t)(b * LLEN + p) * PJW + k * PJC + c];
    }
    if (d < SEGL) posl[d] = pos_map(k, l0 + d) * DIN;
    float w6[RDT];
#pragma unroll
    for (int r = 0; r < RDT; ++r) w6[r] = dtw[(k * DIN + d) * RDT + r];
    const float bias = dtb[k * DIN + d];
    float2 a2[8];
#pragma unroll
    for (int j = 0; j < 8; ++j)
        a2[j] = *(const float2*)&a2g[(k * DIN + d) * NST + 2 * j];
    float2 h2[8];
#pragma unroll
    for (int j = 0; j < 8; ++j) h2[j] = make_float2(0.f, 0.f);
    float T = 0.f;
    __syncthreads();
    const bf16* xg = xconv + (size_t)b * LLEN * DIN + d;
    for (int bt = 0; bt < 4; ++bt) {
        int off7[7]; float xv7[7];
#pragma unroll
        for (int i = 0; i < 7; ++i) off7[i] = posl[bt * 7 + i];
#pragma unroll
        for (int i = 0; i < 7; ++i) xv7[i] = b2f(xg[off7[i]]);
#pragma unroll
        for (int i = 0; i < 7; ++i) {
            const float* rowf = &pl[(bt * 7 + i) * PJS1];
            float4 g0 = *(const float4*)(rowf);
            float2 g1 = *(const float2*)(rowf + 4);
            float dtv = bias;
            dtv = fmaf(g0.x, w6[0], dtv); dtv = fmaf(g0.y, w6[1], dtv);
            dtv = fmaf(g0.z, w6[2], dtv); dtv = fmaf(g0.w, w6[3], dtv);
            dtv = fmaf(g1.x, w6[4], dtv); dtv = fmaf(g1.y, w6[5], dtv);
            dtv = softplusf(dtv);
            T += dtv;
            float2 dt2 = make_float2(dtv, dtv);
            float2 u2 = make_float2(dtv * xv7[i], dtv * xv7[i]);
#pragma unroll
            for (int g = 0; g < 4; ++g) {
                float4 Bv = *(const float4*)(rowf + 8 + 4 * g);
                float2 Blo = make_float2(Bv.x, Bv.y);
                float2 Bhi = make_float2(Bv.z, Bv.w);
                float2 alo = pk_mul(dt2, a2[2 * g]);
                float2 ahi = pk_mul(dt2, a2[2 * g + 1]);
                float2 elo, ehi;
                elo.x = EXP2F(alo.x); elo.y = EXP2F(alo.y);
                ehi.x = EXP2F(ahi.x); ehi.y = EXP2F(ahi.y);
                h2[2 * g]     = pk_fma(h2[2 * g],     elo, pk_mul(u2, Blo));
                h2[2 * g + 1] = pk_fma(h2[2 * g + 1], ehi, pk_mul(u2, Bhi));
            }
        }
    }
    size_t base = ((size_t)bid * DIN + d) * NST;
#pragma unroll
    for (int j = 0; j < 8; ++j) *(float2*)&hloc[base + 2 * j] = h2[j];
    tsum[bid * DIN + d] = T;
}

// ---- K5: exact segment carries (hin aliases hloc: read-before-write) -------
__global__ __launch_bounds__(256) void k5_carry(
    const float* hloc, const float* __restrict__ tsum,
    const float* __restrict__ a2g, float* hin) {
    int g = blockIdx.x * 256 + threadIdx.x;   // over B*K*D*N
    int n = g & 15;
    int dk = g >> 4;
    int d = dk % DIN;
    int bk = dk / DIN;                        // b*4 + k
    int k = bk & 3;
    float a2 = a2g[(k * DIN + d) * NST + n];
    float Hc = 0.f;
    for (int s = 0; s < SSEG; ++s) {
        int bid = bk * SSEG + s;
        size_t idx = ((size_t)bid * DIN + d) * NST + n;
        float hl = hloc[idx];
        float Tv = tsum[bid * DIN + d];
        hin[idx] = Hc;
        Hc = fmaf(EXP2F(a2 * Tv), Hc, hl);
    }
}

// ---- K6: scan pass 2 — one segment per block, packed-fp32, fp32 h-in -------
__global__ __launch_bounds__(192) void k6_scan2(
    const bf16* __restrict__ xconv, const float* __restrict__ proj,
    const float* __restrict__ dtw, const float* __restrict__ dtb,
    const float* __restrict__ a2g, const float* __restrict__ Dsp,
    const float* __restrict__ hin, bf16* __restrict__ ysm) {
    __shared__ float pl[SEGL * PJS];
    __shared__ int posl[SEGL];
    const int bid = blockIdx.x;
    const int s = bid % SSEG;
    const int bk = bid / SSEG;
    const int k = bk & 3, b = bk >> 2;
    const int d = threadIdx.x;
    const int l0 = s * SEGL;
    for (int q = d; q < SEGL * PJC; q += 192) {
        int st = q / PJC, c = q - st * PJC;
        int p = pos_map(k, l0 + st);
        int ofs = (c < 6) ? c : c + 2;
        pl[st * PJS + ofs] = proj[(size_t)(b * LLEN + p) * PJW + k * PJC + c];
    }
    if (d < SEGL) posl[d] = pos_map(k, l0 + d) * DIN;
    float w6[RDT];
#pragma unroll
    for (int r = 0; r < RDT; ++r) w6[r] = dtw[(k * DIN + d) * RDT + r];
    const float bias = dtb[k * DIN + d];
    const float dsv = Dsp[k * DIN + d];
    float2 a2[8];
#pragma unroll
    for (int j = 0; j < 8; ++j)
        a2[j] = *(const float2*)&a2g[(k * DIN + d) * NST + 2 * j];
    float2 h2[8];
    size_t hbase = ((size_t)bid * DIN + d) * NST;
#pragma unroll
    for (int j = 0; j < 8; ++j) h2[j] = *(const float2*)&hin[hbase + 2 * j];
    __syncthreads();
    const bf16* xg = xconv + (size_t)b * LLEN * DIN + d;
    bf16* ysg = ysm + ((size_t)bk * LLEN) * DIN + d;
    for (int bt = 0; bt < 4; ++bt) {
        int off7[7]; float xv7[7];
#pragma unroll
        for (int i = 0; i < 7; ++i) off7[i] = posl[bt * 7 + i];
#pragma unroll
        for (int i = 0; i < 7; ++i) xv7[i] = b2f(xg[off7[i]]);
#pragma unroll
        for (int i = 0; i < 7; ++i) {
            const float* rowf = &pl[(bt * 7 + i) * PJS];
            float4 g0 = *(const float4*)(rowf);
            float2 g1 = *(const float2*)(rowf + 4);
            float dtv = bias;
            dtv = fmaf(g0.x, w6[0], dtv); dtv = fmaf(g0.y, w6[1], dtv);
            dtv = fmaf(g0.z, w6[2], dtv); dtv = fmaf(g0.w, w6[3], dtv);
            dtv = fmaf(g1.x, w6[4], dtv); dtv = fmaf(g1.y, w6[5], dtv);
            dtv = softplusf(dtv);
            float2 dt2 = make_float2(dtv, dtv);
            float2 u2 = make_float2(dtv * xv7[i], dtv * xv7[i]);
            float2 yac0 = make_float2(0.f, 0.f), yac1 = make_float2(0.f, 0.f);
#pragma unroll
            for (int g = 0; g < 4; ++g) {
                float4 Bv = *(const float4*)(rowf + 8 + 4 * g);
                float4 Cv = *(const float4*)(rowf + 24 + 4 * g);
                float2 Blo = make_float2(Bv.x, Bv.y);
                float2 Bhi = make_float2(Bv.z, Bv.w);
                float2 Clo = make_float2(Cv.x, Cv.y);
                float2 Chi = make_float2(Cv.z, Cv.w);
                float2 alo = pk_mul(dt2, a2[2 * g]);
                float2 ahi = pk_mul(dt2, a2[2 * g + 1]);
                float2 elo, ehi;
                elo.x = EXP2F(alo.x); elo.y = EXP2F(alo.y);
                ehi.x = EXP2F(ahi.x); ehi.y = EXP2F(ahi.y);
                h2[2 * g]     = pk_fma(h2[2 * g],     elo, pk_mul(u2, Blo));
                h2[2 * g + 1] = pk_fma(h2[2 * g + 1], ehi, pk_mul(u2, Bhi));
                yac0 = pk_fma(h2[2 * g],     Clo, yac0);
                yac1 = pk_fma(h2[2 * g + 1], Chi, yac1);
            }
            float y = (yac0.x + yac0.y) + (yac1.x + yac1.y);
            ysg[off7[i]] = f2b(fmaf(dsv, xv7[i], y));
        }
    }
}

// ---- K6.5: merge 4 planes + out_norm LN + *silu(z) -------------------------
__global__ __launch_bounds__(256) void k65_merge(
    const bf16* __restrict__ ysm, const bf16* __restrict__ z,
    const float* __restrict__ onw, const float* __restrict__ onb,
    bf16* __restrict__ ymod) {
    __shared__ float rb[16 * DIN];
    __shared__ float ps[256], pq[256];
    __shared__ float mrow[16], srow[16];
    const int t = threadIdx.x;
    const int P0 = blockIdx.x * 16;
    for (int q = t; q < 16 * DIN; q += 256) {
        int pos = q / DIN, c = q - pos * DIN;
        int P = P0 + pos;
        int b = P / LLEN, l = P - b * LLEN;
        size_t base = ((size_t)(b * KDIR) * LLEN + l) * DIN + c;
        size_t pstr = (size_t)LLEN * DIN;
        float v = b2f(ysm[base]) + b2f(ysm[base + pstr]) +
                  b2f(ysm[base + 2 * pstr]) + b2f(ysm[base + 3 * pstr]);
        rb[q] = v;
    }
    __syncthreads();
    {
        int pos = t >> 4, part = t & 15;
        float s = 0.f, s2 = 0.f;
        for (int i = 0; i < 12; ++i) {
            float v = rb[pos * DIN + part * 12 + i];
            s += v; s2 += v * v;
        }
        ps[pos * 16 + part] = s; pq[pos * 16 + part] = s2;
    }
    __syncthreads();
    if (t < 16) {
        float s = 0.f, s2 = 0.f;
        for (int i = 0; i < 16; ++i) { s += ps[t * 16 + i]; s2 += pq[t * 16 + i]; }
        float m = s * (1.f / DIN);
        float v = s2 * (1.f / DIN) - m * m;
        mrow[t] = m; srow[t] = rsqrtf(v + 1e-5f);
    }
    __syncthreads();
    for (int q = t; q < 16 * DIN; q += 256) {
        int pos = q / DIN, c = q - pos * DIN;
        int P = P0 + pos;
        float v = (rb[q] - mrow[pos]) * srow[pos] * onw[c] + onb[c];
        float zv = b2f(z[(size_t)P * DIN + c]);
        v *= zv * sigm(zv);
        ymod[(size_t)P * DIN + c] = f2b(v);
    }
}

extern "C" void kernel_launch(void* const* d_in, const int* in_sizes, int n_in,
                              void* d_out, int out_size, void* d_ws, size_t ws_size,
                              hipStream_t stream) {
    const float* x      = (const float*)d_in[0];
    const float* ln1w   = (const float*)d_in[1];
    const float* ln1b   = (const float*)d_in[2];
    const float* inpW   = (const float*)d_in[3];
    const float* convW  = (const float*)d_in[4];
    const float* convB  = (const float*)d_in[5];
    const float* xprojW = (const float*)d_in[6];
    const float* dtW    = (const float*)d_in[7];
    const float* dtB    = (const float*)d_in[8];
    const float* Alog   = (const float*)d_in[9];
    const float* Dsp    = (const float*)d_in[10];
    const float* onw    = (const float*)d_in[11];
    const float* onb    = (const float*)d_in[12];
    const float* outW   = (const float*)d_in[13];
    const float* ln2w   = (const float*)d_in[14];
    const float* ln2b   = (const float*)d_in[15];
    const float* fc1W   = (const float*)d_in[16];
    const float* fc1b   = (const float*)d_in[17];
    const float* fc2W   = (const float*)d_in[18];
    const float* fc2b   = (const float*)d_in[19];
    float* out = (float*)d_out;

    char* ws = (char*)d_ws;
    // layout (byte offsets; lifetimes verified stage-by-stage):
    unsigned short* z_us    = (unsigned short*)(ws + 0);          // [G1..k65]   9,633,792
    bf16*  z_bf             = (bf16*)z_us;
    bf16*  xconv_bf         = (bf16*)(ws + 9633792);              // [k2..k6]    9,633,792
    float* proj_f           = (float*)(ws + 19267584);            // [G2..k6]   15,253,504
    bf16*  ymod_bf          = (bf16*)(ws + 19267584);             // [k65..G3]  alias proj
    float* tsum_f           = (float*)(ws + 34521088);            // [k4..k5]    2,752,512
    unsigned short* xcpre_us= (unsigned short*)(ws + 39337984);   // [G1..k2]    9,633,792
    float* hloc_f           = (float*)(ws + 39337984);            // [k4..k6]   44,040,192 (alias dead xcpre)
    float* hin_f            = hloc_f;                             // k5 r-b-w alias
    float* y1_f             = (float*)(ws + 39337984);            // [G3..G5]   alias dead hloc
    bf16*  ysm_bf           = (bf16*)(ws + 83378176);             // [k6..k65]  38,535,168
    unsigned short* hmlp_us = (unsigned short*)(ws + 83378176);   // [G4..G5]   alias dead ysm
    float* a2g_f            = (float*)(ws + 121913344);           // [k0..k6]   49,152
    unsigned short* wbf_us  = (unsigned short*)(ws + 121962496);  // [k0w..G5]  316,416 (end 122,278,912)

    k0_pre<<<48, 256, 0, stream>>>(Alog, a2g_f);
    k0w<<<618, 256, 0, stream>>>(inpW, xprojW, outW, fc1W, fc2W, wbf_us);
    gemm_mfma<384, 96, 0, true><<<dim3(196, 6), 256, 0, stream>>>(
        x, wbf_us + 0, nullptr, nullptr, ln1w, ln1b, xcpre_us, z_us);
    k2_conv<<<4704, 256, 0, stream>>>(xcpre_us, convW, convB,
                                      (unsigned short*)xconv_bf);
    gemm_mfma<152, 192, 1, false><<<dim3(196, 3), 256, 0, stream>>>(
        xconv_bf, wbf_us + 36864, nullptr, nullptr, nullptr, nullptr,
        proj_f, nullptr);
    k4_scan1<<<3584, 192, 0, stream>>>(xconv_bf, proj_f, dtW, dtB, a2g_f,
                                       hloc_f, tsum_f);
    k5_carry<<<384, 256, 0, stream>>>(hloc_f, tsum_f, a2g_f, hin_f);
    k6_scan2<<<3584, 192, 0, stream>>>(xconv_bf, proj_f, dtW, dtB, a2g_f, Dsp,
                                       hin_f, ysm_bf);
    k65_merge<<<1568, 256, 0, stream>>>(ysm_bf, z_bf, onw, onb, ymod_bf);
    gemm_mfma<96, 192, 2, false><<<dim3(196, 2), 256, 0, stream>>>(
        ymod_bf, wbf_us + 66048, nullptr, x, nullptr, nullptr, y1_f, nullptr);
    gemm_mfma<384, 96, 3, true><<<dim3(196, 6), 256, 0, stream>>>(
        y1_f, wbf_us + 84480, fc1b, nullptr, ln2w, ln2b, hmlp_us, nullptr);
    gemm_mfma<96, 384, 4, false><<<dim3(196, 2), 256, 0, stream>>>(
        hmlp_us, wbf_us + 121344, fc2b, y1_f, nullptr, nullptr, out, nullptr);
}